// Round 13
// baseline (581.905 us; speedup 1.0000x reference)
//
#include <hip/hip_runtime.h>
#include <hip/hip_cooperative_groups.h>
#include <math.h>

namespace cg = cooperative_groups;

#define NPT 2048
#define KNN 20

typedef const float* fp;
typedef __attribute__((ext_vector_type(4))) float f32x4;
typedef __attribute__((ext_vector_type(8))) short s16x8;

__device__ __forceinline__ ushort f2bf_rne(float v) {
    unsigned u = __float_as_uint(v);
    unsigned r = u + 0x7FFFu + ((u >> 16) & 1u);
    return (ushort)(r >> 16);
}
__device__ __forceinline__ float bfbits2f(ushort h) {
    return __uint_as_float(((unsigned)h) << 16);
}
__device__ __forceinline__ s16x8 ldfrag(const ushort* p) {
    union { uint4 u; s16x8 s; } cv;
    cv.u = *reinterpret_cast<const uint4*>(p);
    return cv.s;
}
__device__ __forceinline__ void f8_hilo(const float* row, s16x8* hi, s16x8* lo) {
    float4 f0 = *reinterpret_cast<const float4*>(row);
    float4 f1 = *reinterpret_cast<const float4*>(row + 4);
    float f[8] = {f0.x, f0.y, f0.z, f0.w, f1.x, f1.y, f1.z, f1.w};
    union { ushort u[8]; s16x8 s; } H, L;
    #pragma unroll
    for (int j = 0; j < 8; j++) {
        ushort h = f2bf_rne(f[j]);
        H.u[j] = h;
        L.u[j] = f2bf_rne(f[j] - bfbits2f(h));
    }
    *hi = H.s; *lo = L.s;
}

struct KParams {
    const float *xbf, *wq, *bq, *wk, *bk, *wv, *bv, *wm, *bm, *w1, *b1;
    const float *gamma, *beta, *w2, *b2;
    float *xx; ushort *xhiF, *xloF;
    ushort *wqFhi, *wqFlo, *wkFhi, *wkFlo, *wvFhi, *wvFlo;
    ushort *wcFhi, *wcFlo, *w2Fhi, *w2Flo;
    float *b1p, *stats, *qT, *kT, *vT, *key0, *key1;
    int* idxb; float *avT, *hbuf, *out;
};

// ---------------------------------------------------------------------------
// Phase 0 (vb in [0,835)): fragify x + xx; weight frags; b1p; stats=0.
// ---------------------------------------------------------------------------
__device__ void phase_prep(const KParams& P, int vb) {
    int t = threadIdx.x;
    if (vb < 256) {
        __shared__ float xs[16][129];
        __shared__ float xpart[16][17];
        int p0 = vb * 16;
        int b = p0 >> 11, n0 = p0 & 2047;
        fp xb = P.xbf + (size_t)b * 128 * NPT;
        {
            int c = t >> 1, half = t & 1;
            float4 f0 = *reinterpret_cast<const float4*>(xb + (size_t)c * NPT + n0 + half * 8);
            float4 f1 = *reinterpret_cast<const float4*>(xb + (size_t)c * NPT + n0 + half * 8 + 4);
            xs[half * 8 + 0][c] = f0.x; xs[half * 8 + 1][c] = f0.y;
            xs[half * 8 + 2][c] = f0.z; xs[half * 8 + 3][c] = f0.w;
            xs[half * 8 + 4][c] = f1.x; xs[half * 8 + 5][c] = f1.y;
            xs[half * 8 + 6][c] = f1.z; xs[half * 8 + 7][c] = f1.w;
        }
        __syncthreads();
        int p = t & 15, g = t >> 4, c0 = g * 8;
        float f[8];
        #pragma unroll
        for (int j = 0; j < 8; j++) f[j] = xs[p][c0 + j];
        float ps = 0.f;
        #pragma unroll
        for (int j = 0; j < 8; j++) ps += f[j] * f[j];
        xpart[p][g] = ps;
        union { ushort u[8]; uint4 q; } H, L;
        #pragma unroll
        for (int j = 0; j < 8; j++) {
            ushort hi = f2bf_rne(f[j]);
            H.u[j] = hi;
            L.u[j] = f2bf_rne(f[j] - bfbits2f(hi));
        }
        size_t off = ((size_t)vb * 4 + (c0 >> 5)) * 512
                   + (size_t)(((((c0 >> 3) & 3) * 16) + p) * 8);
        *reinterpret_cast<uint4*>(P.xhiF + off) = H.q;
        *reinterpret_cast<uint4*>(P.xloF + off) = L.q;
        __syncthreads();
        if (t < 16) {
            float s = 0.f;
            #pragma unroll
            for (int gg = 0; gg < 16; gg++) s += xpart[t][gg];
            P.xx[p0 + t] = s;
        }
        __syncthreads();            // LDS reused next persistent iteration
        return;
    }
    int wid = (vb - 256) * 256 + t;
    if (wid < 49152) {
        int which = wid >> 14, e = wid & 16383;
        int lane = (e >> 3) & 63, j = e & 7, kk = (e >> 9) & 3, nt = e >> 11;
        int n = nt * 16 + (lane & 15);
        int k = kk * 32 + (lane >> 4) * 8 + j;
        fp src = which == 0 ? P.wq : which == 1 ? P.wk : P.wv;
        float v = src[n * 128 + k];
        ushort hi = f2bf_rne(v);
        (which == 0 ? P.wqFhi : which == 1 ? P.wkFhi : P.wvFhi)[e] = hi;
        (which == 0 ? P.wqFlo : which == 1 ? P.wkFlo : P.wvFlo)[e] = f2bf_rne(v - bfbits2f(hi));
    } else if (wid < 114688) {
        int e = wid - 49152;
        int j = e & 7, lane = (e >> 3) & 63, kk = (e >> 9) & 7, nt = e >> 12;
        int n = nt * 16 + (lane & 15);
        int k = kk * 32 + (lane >> 4) * 8 + j;
        float v;
        if (k < 128) {
            v = P.w1[n * 256 + k];
        } else {
            int c = k - 128;
            float s = 0.f;
            for (int i = 0; i < 128; i += 4) {
                float4 wr = *reinterpret_cast<const float4*>(P.w1 + n * 256 + 128 + i);
                s += wr.x * P.wm[(i + 0) * 128 + c];
                s += wr.y * P.wm[(i + 1) * 128 + c];
                s += wr.z * P.wm[(i + 2) * 128 + c];
                s += wr.w * P.wm[(i + 3) * 128 + c];
            }
            v = s;
        }
        ushort hi = f2bf_rne(v);
        P.wcFhi[e] = hi;
        P.wcFlo[e] = f2bf_rne(v - bfbits2f(hi));
    } else if (wid < 147456) {
        int e = wid - 114688;
        int j = e & 7, lane = (e >> 3) & 63, kk = (e >> 9) & 7, nt = e >> 12;
        int n = nt * 16 + (lane & 15);
        int k = kk * 32 + (lane >> 4) * 8 + j;
        float v = P.w2[n * 256 + k];
        ushort hi = f2bf_rne(v);
        P.w2Fhi[e] = hi;
        P.w2Flo[e] = f2bf_rne(v - bfbits2f(hi));
    } else if (wid < 147712) {
        int o = wid - 147456;
        float s = P.b1[o];
        for (int i = 0; i < 128; i++)
            s += P.w1[o * 256 + 128 + i] * P.bm[i];
        P.b1p[o] = s;
    } else if (wid < 148224) {
        P.stats[wid - 147712] = 0.0f;
    }
}

// ---------------------------------------------------------------------------
// Phase 1 (vb in [0,2432)): [0,384) qkv GEMM; rest key GEMM slabs 0/1.
// ---------------------------------------------------------------------------
__device__ void phase_gemm(const KParams& P, int vb) {
    int t = threadIdx.x, wvi = t >> 6, lane = t & 63;
    if (vb < 384) {
        int gw = vb * 4 + wvi;
        int rt = gw / 6, rem = gw - rt * 6;
        int mat = rem >> 1, hf = rem & 1;
        const ushort* whi = mat == 0 ? P.wqFhi : mat == 1 ? P.wkFhi : P.wvFhi;
        const ushort* wlo = mat == 0 ? P.wqFlo : mat == 1 ? P.wkFlo : P.wvFlo;
        fp bias    = mat == 0 ? P.bq : mat == 1 ? P.bk : P.bv;
        float* out = mat == 0 ? P.qT : mat == 1 ? P.kT : P.vT;
        f32x4 acc[4];
        #pragma unroll
        for (int j = 0; j < 4; j++) acc[j] = (f32x4){0.f, 0.f, 0.f, 0.f};
        for (int kk = 0; kk < 4; kk++) {
            s16x8 ahi = ldfrag(P.xhiF + ((size_t)(rt * 4 + kk)) * 512 + lane * 8);
            s16x8 alo = ldfrag(P.xloF + ((size_t)(rt * 4 + kk)) * 512 + lane * 8);
            #pragma unroll
            for (int j = 0; j < 4; j++) {
                int nt = hf * 4 + j;
                s16x8 bhi = ldfrag(whi + ((size_t)(nt * 4 + kk)) * 512 + lane * 8);
                s16x8 blo = ldfrag(wlo + ((size_t)(nt * 4 + kk)) * 512 + lane * 8);
                acc[j] = __builtin_amdgcn_mfma_f32_16x16x32_bf16(ahi, bhi, acc[j], 0, 0, 0);
                acc[j] = __builtin_amdgcn_mfma_f32_16x16x32_bf16(alo, bhi, acc[j], 0, 0, 0);
                acc[j] = __builtin_amdgcn_mfma_f32_16x16x32_bf16(ahi, blo, acc[j], 0, 0, 0);
            }
        }
        int cl = lane & 15, quad = lane >> 4, p0 = rt * 16;
        #pragma unroll
        for (int j = 0; j < 4; j++) {
            int o = hf * 64 + j * 16 + cl;
            float bvv = bias[o];
            #pragma unroll
            for (int r = 0; r < 4; r++)
                out[(size_t)(p0 + quad * 4 + r) * 128 + o] = acc[j][r] + bvv;
        }
        return;
    }
    int slab = (vb >= 1408) ? 1 : 0;
    int lb = vb - 384 - slab * 1024;
    int gw = lb * 4 + wvi;
    int rtl = gw >> 5, cs = gw & 31;
    int b = slab;
    int rt = slab * 128 + rtl;
    float* key = slab ? P.key1 : P.key0;

    f32x4 acc[4];
    #pragma unroll
    for (int j = 0; j < 4; j++) acc[j] = (f32x4){0.f, 0.f, 0.f, 0.f};
    for (int kk = 0; kk < 4; kk++) {
        s16x8 ahi = ldfrag(P.xhiF + ((size_t)(rt * 4 + kk)) * 512 + lane * 8);
        s16x8 alo = ldfrag(P.xloF + ((size_t)(rt * 4 + kk)) * 512 + lane * 8);
        #pragma unroll
        for (int j = 0; j < 4; j++) {
            int ct = b * 128 + cs * 4 + j;
            s16x8 bhi = ldfrag(P.xhiF + ((size_t)(ct * 4 + kk)) * 512 + lane * 8);
            s16x8 blo = ldfrag(P.xloF + ((size_t)(ct * 4 + kk)) * 512 + lane * 8);
            acc[j] = __builtin_amdgcn_mfma_f32_16x16x32_bf16(ahi, bhi, acc[j], 0, 0, 0);
            acc[j] = __builtin_amdgcn_mfma_f32_16x16x32_bf16(alo, bhi, acc[j], 0, 0, 0);
            acc[j] = __builtin_amdgcn_mfma_f32_16x16x32_bf16(ahi, blo, acc[j], 0, 0, 0);
        }
    }
    int cl = lane & 15, quad = lane >> 4;
    #pragma unroll
    for (int j = 0; j < 4; j++) {
        int col = cs * 64 + j * 16 + cl;
        float xxv = P.xx[b * 2048 + col];
        #pragma unroll
        for (int r = 0; r < 4; r++)
            key[(size_t)(rtl * 16 + quad * 4 + r) * 2048 + col] = 2.0f * acc[j][r] - xxv;
    }
}

// ---------------------------------------------------------------------------
// Phase 2 (vb in [0,1024)): per-row top-20 with exact threshold prefilter.
// ---------------------------------------------------------------------------
#define MERGE(off) { float ov = __shfl_xor(bv, off); int oi = __shfl_xor(bi, off); \
                     if (ov > bv || (ov == bv && oi < bi)) { bv = ov; bi = oi; } }

__device__ void phase_topk(const KParams& P, int vb) {
    __shared__ float sv[4][256];
    __shared__ int   si[4][256];
    int t = threadIdx.x, w = t >> 6, lane = t & 63;
    int slab = vb >> 9;
    int rowl = (vb & 511) * 4 + w;
    const float* key = slab ? P.key1 : P.key0;
    int rowbase = slab * 2048;
    const float4* kr = reinterpret_cast<const float4*>(key + (size_t)rowl * 2048);
    float rv[32];
    #pragma unroll
    for (int j = 0; j < 8; j++) {
        float4 v = kr[j * 64 + lane];
        rv[j * 4 + 0] = v.x; rv[j * 4 + 1] = v.y;
        rv[j * 4 + 2] = v.z; rv[j * 4 + 3] = v.w;
    }
    float lm = rv[0];
    #pragma unroll
    for (int sl = 1; sl < 32; sl++) lm = fmaxf(lm, rv[sl]);
    float bs = lm;
    #pragma unroll
    for (int k = 2; k <= 64; k <<= 1) {
        #pragma unroll
        for (int j = k >> 1; j > 0; j >>= 1) {
            float o = __shfl_xor(bs, j);
            bool dirDesc = (lane & k) != 0;
            bool upper   = (lane & j) != 0;
            bs = (upper != dirDesc) ? fmaxf(bs, o) : fminf(bs, o);
        }
    }
    float T = __shfl(bs, 44);
    int cnt = 0;
    #pragma unroll
    for (int sl = 0; sl < 32; sl++) cnt += (rv[sl] >= T) ? 1 : 0;
    int inc = cnt;
    #pragma unroll
    for (int off = 1; off < 64; off <<= 1) {
        int o = __shfl_up(inc, off);
        if (lane >= off) inc += o;
    }
    int S = __shfl(inc, 63);
    int pos = inc - cnt;
    bool small = (S <= 256);
    if (small) {
        #pragma unroll
        for (int sl = 0; sl < 32; sl++) {
            if (rv[sl] >= T) {
                sv[w][pos] = rv[sl];
                si[w][pos] = (sl >> 2) * 256 + lane * 4 + (sl & 3);
                pos++;
            }
        }
    }
    __syncthreads();

    if (small) {
        float vl[4]; int il[4];
        #pragma unroll
        for (int s = 0; s < 4; s++) {
            int g = lane + s * 64;
            bool ok = g < S;
            vl[s] = ok ? sv[w][g] : -3.4e38f;
            il[s] = ok ? si[w][g] : 0x7FFFFFFF;
        }
        unsigned removed = 0u;
        for (int iter = 0; iter < KNN; iter++) {
            float bv = -3.4e38f; int bi = 0x7FFFFFFF;
            #pragma unroll
            for (int s = 0; s < 4; s++) {
                bool live = ((removed >> s) & 1u) == 0u;
                if (live && (vl[s] > bv || (vl[s] == bv && il[s] < bi))) {
                    bv = vl[s]; bi = il[s];
                }
            }
            MERGE(32) MERGE(16) MERGE(8) MERGE(4) MERGE(2) MERGE(1)
            if (lane == 0) P.idxb[(size_t)(rowbase + rowl) * KNN + iter] = bi & 2047;
            #pragma unroll
            for (int s = 0; s < 4; s++)
                if (il[s] == bi) removed |= 1u << s;
        }
    } else {
        unsigned removed = 0u;
        for (int iter = 0; iter < KNN; iter++) {
            float bv = -3.4e38f; int bi = 0;
            #pragma unroll
            for (int sl = 0; sl < 32; sl++) {
                bool live = ((removed >> sl) & 1u) == 0u;
                if (live && rv[sl] > bv) { bv = rv[sl]; bi = (sl >> 2) * 256 + lane * 4 + (sl & 3); }
            }
            MERGE(32) MERGE(16) MERGE(8) MERGE(4) MERGE(2) MERGE(1)
            bi &= 2047;
            if (lane == 0) P.idxb[(size_t)(rowbase + rowl) * KNN + iter] = bi;
            if (((bi >> 2) & 63) == lane) removed |= 1u << ((bi >> 8) * 4 + (bi & 3));
        }
    }
    __syncthreads();                // LDS reused next persistent iteration
}

// ---------------------------------------------------------------------------
// Phase 3 (vb in [0,2048)): sparse mutual-KNN attention, 2 points per vb.
// ---------------------------------------------------------------------------
__device__ void phase_attn(const KParams& P, int vb) {
    __shared__ float sbuf[2][KNN * 4];
    __shared__ int   mlist[2][KNN];
    __shared__ int   cnt_s[2];
    int tt = threadIdx.x;
    int half = tt >> 7, t = tt & 127;
    int p = vb * 2 + half;
    int b = p >> 11, n = p & 2047;
    int bbase = b * NPT;
    int h = t >> 5;

    if ((tt >> 6) == half * 2) {
        int lane = tt & 63;
        bool fl = false; int m = 0;
        if (lane < KNN) {
            m = P.idxb[(size_t)p * KNN + lane] & 2047;
            const int4* mrow = reinterpret_cast<const int4*>(P.idxb + (size_t)(bbase + m) * KNN);
            int4 r0 = mrow[0], r1 = mrow[1], r2 = mrow[2], r3 = mrow[3], r4 = mrow[4];
            fl = (r0.x == n) || (r0.y == n) || (r0.z == n) || (r0.w == n)
              || (r1.x == n) || (r1.y == n) || (r1.z == n) || (r1.w == n)
              || (r2.x == n) || (r2.y == n) || (r2.z == n) || (r2.w == n)
              || (r3.x == n) || (r3.y == n) || (r3.z == n) || (r3.w == n)
              || (r4.x == n) || (r4.y == n) || (r4.z == n) || (r4.w == n);
        }
        unsigned long long mask = __ballot(fl);
        int pos = __popcll(mask & ((1ull << lane) - 1ull));
        if (fl) mlist[half][pos] = m;
        if (lane == 0) cnt_s[half] = (int)__popcll(mask);
    }
    __syncthreads();

    int cnt = cnt_s[half];
    float qv = P.qT[(size_t)p * 128 + t];
    for (int jj = 0; jj < cnt; jj++) {
        int m = mlist[half][jj];
        float prod = qv * P.kT[(size_t)(bbase + m) * 128 + t];
        prod += __shfl_xor(prod, 16);
        prod += __shfl_xor(prod, 8);
        prod += __shfl_xor(prod, 4);
        prod += __shfl_xor(prod, 2);
        prod += __shfl_xor(prod, 1);
        if ((t & 31) == 0) sbuf[half][jj * 4 + h] = prod * 0.17677669529663687f;
    }
    __syncthreads();

    float mx = -3.4e38f;
    for (int j = 0; j < cnt; j++) mx = fmaxf(mx, sbuf[half][j * 4 + h]);
    float den = 0.f;
    for (int j = 0; j < cnt; j++) den += expf(sbuf[half][j * 4 + h] - mx);
    float inv = (cnt > 0) ? (1.0f / den) : 0.0f;
    float acc = 0.f;
    for (int j = 0; j < cnt; j++) {
        float pw = expf(sbuf[half][j * 4 + h] - mx) * inv;
        acc += pw * P.vT[(size_t)(bbase + mlist[half][j]) * 128 + t];
    }
    P.avT[(size_t)p * 128 + t] = acc;
    __syncthreads();                // LDS reused next persistent iteration
}

// ---------------------------------------------------------------------------
// Phase 4 (vb in [0,256)): h = w1x@x + W@av + b1p (MFMA K=256) + BN stats.
// ---------------------------------------------------------------------------
__device__ void phase_h(const KParams& P, int vb) {
    int t = threadIdx.x, cs = t >> 6, lane = t & 63;
    int rt = vb;
    int p0 = rt * 16;

    f32x4 acc[4];
    #pragma unroll
    for (int j = 0; j < 4; j++) acc[j] = (f32x4){0.f, 0.f, 0.f, 0.f};

    for (int kk = 0; kk < 8; kk++) {
        s16x8 ahi, alo;
        if (kk < 4) {
            ahi = ldfrag(P.xhiF + ((size_t)(rt * 4 + kk)) * 512 + lane * 8);
            alo = ldfrag(P.xloF + ((size_t)(rt * 4 + kk)) * 512 + lane * 8);
        } else {
            const float* arow = P.avT + (size_t)(p0 + (lane & 15)) * 128
                              + (kk - 4) * 32 + (lane >> 4) * 8;
            f8_hilo(arow, &ahi, &alo);
        }
        #pragma unroll
        for (int j = 0; j < 4; j++) {
            int nt = cs * 4 + j;
            s16x8 bhi = ldfrag(P.wcFhi + ((size_t)(nt * 8 + kk)) * 512 + lane * 8);
            s16x8 blo = ldfrag(P.wcFlo + ((size_t)(nt * 8 + kk)) * 512 + lane * 8);
            acc[j] = __builtin_amdgcn_mfma_f32_16x16x32_bf16(ahi, bhi, acc[j], 0, 0, 0);
            acc[j] = __builtin_amdgcn_mfma_f32_16x16x32_bf16(alo, bhi, acc[j], 0, 0, 0);
            acc[j] = __builtin_amdgcn_mfma_f32_16x16x32_bf16(ahi, blo, acc[j], 0, 0, 0);
        }
    }

    int cl = lane & 15, quad = lane >> 4;
    #pragma unroll
    for (int j = 0; j < 4; j++) {
        int o = cs * 64 + j * 16 + cl;
        float bb = P.b1p[o];
        float s = 0.f, s2 = 0.f;
        #pragma unroll
        for (int r = 0; r < 4; r++) {
            float v = acc[j][r] + bb;
            P.hbuf[(size_t)(p0 + quad * 4 + r) * 256 + o] = v;
            s += v; s2 += v * v;
        }
        s  += __shfl_xor(s, 16);  s  += __shfl_xor(s, 32);
        s2 += __shfl_xor(s2, 16); s2 += __shfl_xor(s2, 32);
        if (quad == 0) {
            atomicAdd(&P.stats[o], s);
            atomicAdd(&P.stats[256 + o], s2);
        }
    }
}

// ---------------------------------------------------------------------------
// Phase 5 (vb in [0,256)): out = w2@relu(BN(h)) + b2 + x (MFMA K=256).
// ---------------------------------------------------------------------------
__device__ void phase_out(const KParams& P, int vb) {
    int t = threadIdx.x, wvi = t >> 6, lane = t & 63;
    int rt = vb;
    int p0 = rt * 16;

    f32x4 acc[2];
    acc[0] = (f32x4){0.f, 0.f, 0.f, 0.f};
    acc[1] = (f32x4){0.f, 0.f, 0.f, 0.f};

    for (int kk = 0; kk < 8; kk++) {
        int c0 = kk * 32 + (lane >> 4) * 8;
        const float* hrow = P.hbuf + (size_t)(p0 + (lane & 15)) * 256 + c0;
        float4 f0 = *reinterpret_cast<const float4*>(hrow);
        float4 f1 = *reinterpret_cast<const float4*>(hrow + 4);
        float4 s0 = *reinterpret_cast<const float4*>(P.stats + c0);
        float4 s1 = *reinterpret_cast<const float4*>(P.stats + c0 + 4);
        float4 q0 = *reinterpret_cast<const float4*>(P.stats + 256 + c0);
        float4 q1 = *reinterpret_cast<const float4*>(P.stats + 256 + c0 + 4);
        float4 g0 = *reinterpret_cast<const float4*>(P.gamma + c0);
        float4 g1 = *reinterpret_cast<const float4*>(P.gamma + c0 + 4);
        float4 e0 = *reinterpret_cast<const float4*>(P.beta + c0);
        float4 e1 = *reinterpret_cast<const float4*>(P.beta + c0 + 4);
        float f[8] = {f0.x, f0.y, f0.z, f0.w, f1.x, f1.y, f1.z, f1.w};
        float sm[8] = {s0.x, s0.y, s0.z, s0.w, s1.x, s1.y, s1.z, s1.w};
        float sq[8] = {q0.x, q0.y, q0.z, q0.w, q1.x, q1.y, q1.z, q1.w};
        float gm[8] = {g0.x, g0.y, g0.z, g0.w, g1.x, g1.y, g1.z, g1.w};
        float bt[8] = {e0.x, e0.y, e0.z, e0.w, e1.x, e1.y, e1.z, e1.w};
        union { ushort u[8]; s16x8 s; } H, L;
        #pragma unroll
        for (int j = 0; j < 8; j++) {
            float mu  = sm[j] * (1.0f / 4096.0f);
            float var = fmaxf(sq[j] * (1.0f / 4096.0f) - mu * mu, 0.0f);
            float a    = gm[j] / sqrtf(var + 1e-5f);
            float cadd = bt[j] - mu * a;
            float v = fmaxf(f[j] * a + cadd, 0.0f);
            ushort hi = f2bf_rne(v);
            H.u[j] = hi;
            L.u[j] = f2bf_rne(v - bfbits2f(hi));
        }
        s16x8 ahi = H.s, alo = L.s;
        #pragma unroll
        for (int jj = 0; jj < 2; jj++) {
            int nt = wvi * 2 + jj;
            s16x8 bhi = ldfrag(P.w2Fhi + ((size_t)(nt * 8 + kk)) * 512 + lane * 8);
            s16x8 blo = ldfrag(P.w2Flo + ((size_t)(nt * 8 + kk)) * 512 + lane * 8);
            acc[jj] = __builtin_amdgcn_mfma_f32_16x16x32_bf16(ahi, bhi, acc[jj], 0, 0, 0);
            acc[jj] = __builtin_amdgcn_mfma_f32_16x16x32_bf16(alo, bhi, acc[jj], 0, 0, 0);
            acc[jj] = __builtin_amdgcn_mfma_f32_16x16x32_bf16(ahi, blo, acc[jj], 0, 0, 0);
        }
    }
    int cl = lane & 15, quad = lane >> 4;
    int b = p0 >> 11, n0 = p0 & 2047;
    #pragma unroll
    for (int jj = 0; jj < 2; jj++) {
        int o = (wvi * 2 + jj) * 16 + cl;
        float bb = P.b2[o];
        size_t base = (size_t)b * 128 * NPT + (size_t)o * NPT + n0 + quad * 4;
        float4 xv = *reinterpret_cast<const float4*>(P.xbf + base);
        float4 ov;
        ov.x = acc[jj][0] + bb + xv.x;
        ov.y = acc[jj][1] + bb + xv.y;
        ov.z = acc[jj][2] + bb + xv.z;
        ov.w = acc[jj][3] + bb + xv.w;
        *reinterpret_cast<float4*>(P.out + base) = ov;
    }
}

// ---------------------------------------------------------------------------
// mega: all 6 phases in one cooperative kernel, grid-stride + grid.sync().
// ---------------------------------------------------------------------------
__global__ __launch_bounds__(256, 2) void mega(KParams P) {
    cg::grid_group g = cg::this_grid();
    for (int vb = blockIdx.x; vb < 835; vb += gridDim.x) phase_prep(P, vb);
    __threadfence(); g.sync();
    for (int vb = blockIdx.x; vb < 2432; vb += gridDim.x) phase_gemm(P, vb);
    __threadfence(); g.sync();
    for (int vb = blockIdx.x; vb < 1024; vb += gridDim.x) phase_topk(P, vb);
    __threadfence(); g.sync();
    for (int vb = blockIdx.x; vb < 2048; vb += gridDim.x) phase_attn(P, vb);
    __threadfence(); g.sync();
    for (int vb = blockIdx.x; vb < 256; vb += gridDim.x) phase_h(P, vb);
    __threadfence(); g.sync();
    for (int vb = blockIdx.x; vb < 256; vb += gridDim.x) phase_out(P, vb);
}

// Fallback wrappers (6-dispatch path, identical math)
__global__ __launch_bounds__(256) void w_prep(KParams P) { phase_prep(P, blockIdx.x); }
__global__ __launch_bounds__(256) void w_gemm(KParams P) { phase_gemm(P, blockIdx.x); }
__global__ __launch_bounds__(256) void w_topk(KParams P) { phase_topk(P, blockIdx.x); }
__global__ __launch_bounds__(256) void w_attn(KParams P) { phase_attn(P, blockIdx.x); }
__global__ __launch_bounds__(256) void w_h(KParams P)    { phase_h(P, blockIdx.x); }
__global__ __launch_bounds__(256) void w_out(KParams P)  { phase_out(P, blockIdx.x); }

// ---------------------------------------------------------------------------
// Workspace layout (44,978,176 B; observed ws ≈ 268 MB): same as round 12.
// ---------------------------------------------------------------------------
#define WS_FULL 44978176u

extern "C" void kernel_launch(void* const* d_in, const int* in_sizes, int n_in,
                              void* d_out, int out_size, void* d_ws, size_t ws_size,
                              hipStream_t stream) {
    if (ws_size < (size_t)WS_FULL) return;  // all-zero out => ws too small

    char* ws = (char*)d_ws;
    KParams P;
    P.xbf = (fp)d_in[0];
    P.wq = (fp)d_in[1];  P.bq = (fp)d_in[2];
    P.wk = (fp)d_in[3];  P.bk = (fp)d_in[4];
    P.wv = (fp)d_in[5];  P.bv = (fp)d_in[6];
    P.wm = (fp)d_in[7];  P.bm = (fp)d_in[8];
    P.w1 = (fp)d_in[9];  P.b1 = (fp)d_in[10];
    P.gamma = (fp)d_in[11]; P.beta = (fp)d_in[12];
    P.w2 = (fp)d_in[13]; P.b2 = (fp)d_in[14];
    P.qT    = (float*) (ws + 0);
    P.kT    = (float*) (ws + 2097152);
    P.vT    = (float*) (ws + 4194304);
    P.avT   = (float*) (ws + 6291456);
    P.xx    = (float*) (ws + 8388608);
    P.idxb  = (int*)   (ws + 8404992);
    P.stats = (float*) (ws + 8732672);
    P.b1p   = (float*) (ws + 8734720);
    P.wqFhi = (ushort*)(ws + 8736768);
    P.wqFlo = (ushort*)(ws + 8769536);
    P.wkFhi = (ushort*)(ws + 8802304);
    P.wkFlo = (ushort*)(ws + 8835072);
    P.wvFhi = (ushort*)(ws + 8867840);
    P.wvFlo = (ushort*)(ws + 8900608);
    P.wcFhi = (ushort*)(ws + 8933376);
    P.wcFlo = (ushort*)(ws + 9064448);
    P.w2Fhi = (ushort*)(ws + 9195520);
    P.w2Flo = (ushort*)(ws + 9261056);
    P.xhiF  = (ushort*)(ws + 9326592);
    P.xloF  = (ushort*)(ws + 10375168);
    P.key0  = (float*) (ws + 11423744);
    P.key1  = (float*) (ws + 28200960);
    P.hbuf  = (float*) (ws + 0);            // aliases qT+kT (dead after attn)
    P.out   = (float*)d_out;

    // Try single cooperative mega-kernel; fall back to 6 dispatches.
    int nb = 0;
    hipError_t e = hipOccupancyMaxActiveBlocksPerMultiprocessor(
        &nb, (const void*)mega, 256, 0);
    bool coop = (e == hipSuccess && nb > 0);
    if (coop) {
        int grid = nb * 256;                // 256 CUs on MI355X
        if (grid > 1024) grid = 1024;
        void* args[] = { (void*)&P };
        e = hipLaunchCooperativeKernel((const void*)mega, dim3(grid), dim3(256),
                                       args, 0, stream);
        coop = (e == hipSuccess);
    }
    if (!coop) {
        w_prep<<<835, 256, 0, stream>>>(P);
        w_gemm<<<2432, 256, 0, stream>>>(P);
        w_topk<<<1024, 256, 0, stream>>>(P);
        w_attn<<<2048, 256, 0, stream>>>(P);
        w_h<<<256, 256, 0, stream>>>(P);
        w_out<<<256, 256, 0, stream>>>(P);
    }
}

// Round 14
// 195.774 us; speedup vs baseline: 2.9723x; 2.9723x over previous
//
#include <hip/hip_runtime.h>
#include <math.h>

#define NPT 2048
#define KNN 20

typedef const float* fp;
typedef __attribute__((ext_vector_type(4))) float f32x4;
typedef __attribute__((ext_vector_type(8))) short s16x8;

__device__ __forceinline__ ushort f2bf_rne(float v) {
    unsigned u = __float_as_uint(v);
    unsigned r = u + 0x7FFFu + ((u >> 16) & 1u);
    return (ushort)(r >> 16);
}
__device__ __forceinline__ float bfbits2f(ushort h) {
    return __uint_as_float(((unsigned)h) << 16);
}
__device__ __forceinline__ s16x8 ldfrag(const ushort* p) {
    union { uint4 u; s16x8 s; } cv;
    cv.u = *reinterpret_cast<const uint4*>(p);
    return cv.s;
}
__device__ __forceinline__ void f8_hilo(const float* row, s16x8* hi, s16x8* lo) {
    float4 f0 = *reinterpret_cast<const float4*>(row);
    float4 f1 = *reinterpret_cast<const float4*>(row + 4);
    float f[8] = {f0.x, f0.y, f0.z, f0.w, f1.x, f1.y, f1.z, f1.w};
    union { ushort u[8]; s16x8 s; } H, L;
    #pragma unroll
    for (int j = 0; j < 8; j++) {
        ushort h = f2bf_rne(f[j]);
        H.u[j] = h;
        L.u[j] = f2bf_rne(f[j] - bfbits2f(h));
    }
    *hi = H.s; *lo = L.s;
}

struct KParams {
    const float *xbf, *wq, *bq, *wk, *bk, *wv, *bv, *wm, *bm, *w1, *b1;
    const float *gamma, *beta, *w2, *b2;
    float *xx; ushort *xhiF, *xloF;
    ushort *wqFhi, *wqFlo, *wkFhi, *wkFlo, *wvFhi, *wvFlo;
    ushort *wcFhi, *wcFlo, *w2Fhi, *w2Flo;
    float *b1p, *stats, *qT, *kT, *vT, *key0, *key1;
    int* idxb; float *avT, *hbuf, *out;
};

// ---------------------------------------------------------------------------
// Phase 0 (vb in [0,835)): fragify x + xx; weight frags; b1p; stats=0.
// ---------------------------------------------------------------------------
__device__ void phase_prep(const KParams& P, int vb) {
    int t = threadIdx.x;
    if (vb < 256) {
        __shared__ float xs[16][129];
        __shared__ float xpart[16][17];
        int p0 = vb * 16;
        int b = p0 >> 11, n0 = p0 & 2047;
        fp xb = P.xbf + (size_t)b * 128 * NPT;
        {
            int c = t >> 1, half = t & 1;
            float4 f0 = *reinterpret_cast<const float4*>(xb + (size_t)c * NPT + n0 + half * 8);
            float4 f1 = *reinterpret_cast<const float4*>(xb + (size_t)c * NPT + n0 + half * 8 + 4);
            xs[half * 8 + 0][c] = f0.x; xs[half * 8 + 1][c] = f0.y;
            xs[half * 8 + 2][c] = f0.z; xs[half * 8 + 3][c] = f0.w;
            xs[half * 8 + 4][c] = f1.x; xs[half * 8 + 5][c] = f1.y;
            xs[half * 8 + 6][c] = f1.z; xs[half * 8 + 7][c] = f1.w;
        }
        __syncthreads();
        int p = t & 15, g = t >> 4, c0 = g * 8;
        float f[8];
        #pragma unroll
        for (int j = 0; j < 8; j++) f[j] = xs[p][c0 + j];
        float ps = 0.f;
        #pragma unroll
        for (int j = 0; j < 8; j++) ps += f[j] * f[j];
        xpart[p][g] = ps;
        union { ushort u[8]; uint4 q; } H, L;
        #pragma unroll
        for (int j = 0; j < 8; j++) {
            ushort hi = f2bf_rne(f[j]);
            H.u[j] = hi;
            L.u[j] = f2bf_rne(f[j] - bfbits2f(hi));
        }
        size_t off = ((size_t)vb * 4 + (c0 >> 5)) * 512
                   + (size_t)(((((c0 >> 3) & 3) * 16) + p) * 8);
        *reinterpret_cast<uint4*>(P.xhiF + off) = H.q;
        *reinterpret_cast<uint4*>(P.xloF + off) = L.q;
        __syncthreads();
        if (t < 16) {
            float s = 0.f;
            #pragma unroll
            for (int gg = 0; gg < 16; gg++) s += xpart[t][gg];
            P.xx[p0 + t] = s;
        }
        return;
    }
    int wid = (vb - 256) * 256 + t;
    if (wid < 49152) {
        int which = wid >> 14, e = wid & 16383;
        int lane = (e >> 3) & 63, j = e & 7, kk = (e >> 9) & 3, nt = e >> 11;
        int n = nt * 16 + (lane & 15);
        int k = kk * 32 + (lane >> 4) * 8 + j;
        fp src = which == 0 ? P.wq : which == 1 ? P.wk : P.wv;
        float v = src[n * 128 + k];
        ushort hi = f2bf_rne(v);
        (which == 0 ? P.wqFhi : which == 1 ? P.wkFhi : P.wvFhi)[e] = hi;
        (which == 0 ? P.wqFlo : which == 1 ? P.wkFlo : P.wvFlo)[e] = f2bf_rne(v - bfbits2f(hi));
    } else if (wid < 114688) {
        int e = wid - 49152;
        int j = e & 7, lane = (e >> 3) & 63, kk = (e >> 9) & 7, nt = e >> 12;
        int n = nt * 16 + (lane & 15);
        int k = kk * 32 + (lane >> 4) * 8 + j;
        float v;
        if (k < 128) {
            v = P.w1[n * 256 + k];
        } else {
            int c = k - 128;
            float s = 0.f;
            for (int i = 0; i < 128; i += 4) {
                float4 wr = *reinterpret_cast<const float4*>(P.w1 + n * 256 + 128 + i);
                s += wr.x * P.wm[(i + 0) * 128 + c];
                s += wr.y * P.wm[(i + 1) * 128 + c];
                s += wr.z * P.wm[(i + 2) * 128 + c];
                s += wr.w * P.wm[(i + 3) * 128 + c];
            }
            v = s;
        }
        ushort hi = f2bf_rne(v);
        P.wcFhi[e] = hi;
        P.wcFlo[e] = f2bf_rne(v - bfbits2f(hi));
    } else if (wid < 147456) {
        int e = wid - 114688;
        int j = e & 7, lane = (e >> 3) & 63, kk = (e >> 9) & 7, nt = e >> 12;
        int n = nt * 16 + (lane & 15);
        int k = kk * 32 + (lane >> 4) * 8 + j;
        float v = P.w2[n * 256 + k];
        ushort hi = f2bf_rne(v);
        P.w2Fhi[e] = hi;
        P.w2Flo[e] = f2bf_rne(v - bfbits2f(hi));
    } else if (wid < 147712) {
        int o = wid - 147456;
        float s = P.b1[o];
        for (int i = 0; i < 128; i++)
            s += P.w1[o * 256 + 128 + i] * P.bm[i];
        P.b1p[o] = s;
    } else if (wid < 148224) {
        P.stats[wid - 147712] = 0.0f;
    }
}

// ---------------------------------------------------------------------------
// Phase 1 (vb in [0,2432)): [0,384) qkv GEMM; rest key GEMM slabs 0/1.
// ---------------------------------------------------------------------------
__device__ void phase_gemm(const KParams& P, int vb) {
    int t = threadIdx.x, wvi = t >> 6, lane = t & 63;
    if (vb < 384) {
        int gw = vb * 4 + wvi;
        int rt = gw / 6, rem = gw - rt * 6;
        int mat = rem >> 1, hf = rem & 1;
        const ushort* whi = mat == 0 ? P.wqFhi : mat == 1 ? P.wkFhi : P.wvFhi;
        const ushort* wlo = mat == 0 ? P.wqFlo : mat == 1 ? P.wkFlo : P.wvFlo;
        fp bias    = mat == 0 ? P.bq : mat == 1 ? P.bk : P.bv;
        float* out = mat == 0 ? P.qT : mat == 1 ? P.kT : P.vT;
        f32x4 acc[4];
        #pragma unroll
        for (int j = 0; j < 4; j++) acc[j] = (f32x4){0.f, 0.f, 0.f, 0.f};
        for (int kk = 0; kk < 4; kk++) {
            s16x8 ahi = ldfrag(P.xhiF + ((size_t)(rt * 4 + kk)) * 512 + lane * 8);
            s16x8 alo = ldfrag(P.xloF + ((size_t)(rt * 4 + kk)) * 512 + lane * 8);
            #pragma unroll
            for (int j = 0; j < 4; j++) {
                int nt = hf * 4 + j;
                s16x8 bhi = ldfrag(whi + ((size_t)(nt * 4 + kk)) * 512 + lane * 8);
                s16x8 blo = ldfrag(wlo + ((size_t)(nt * 4 + kk)) * 512 + lane * 8);
                acc[j] = __builtin_amdgcn_mfma_f32_16x16x32_bf16(ahi, bhi, acc[j], 0, 0, 0);
                acc[j] = __builtin_amdgcn_mfma_f32_16x16x32_bf16(alo, bhi, acc[j], 0, 0, 0);
                acc[j] = __builtin_amdgcn_mfma_f32_16x16x32_bf16(ahi, blo, acc[j], 0, 0, 0);
            }
        }
        int cl = lane & 15, quad = lane >> 4, p0 = rt * 16;
        #pragma unroll
        for (int j = 0; j < 4; j++) {
            int o = hf * 64 + j * 16 + cl;
            float bvv = bias[o];
            #pragma unroll
            for (int r = 0; r < 4; r++)
                out[(size_t)(p0 + quad * 4 + r) * 128 + o] = acc[j][r] + bvv;
        }
        return;
    }
    int slab = (vb >= 1408) ? 1 : 0;
    int lb = vb - 384 - slab * 1024;
    int gw = lb * 4 + wvi;
    int rtl = gw >> 5, cs = gw & 31;
    int b = slab;
    int rt = slab * 128 + rtl;
    float* key = slab ? P.key1 : P.key0;

    f32x4 acc[4];
    #pragma unroll
    for (int j = 0; j < 4; j++) acc[j] = (f32x4){0.f, 0.f, 0.f, 0.f};
    for (int kk = 0; kk < 4; kk++) {
        s16x8 ahi = ldfrag(P.xhiF + ((size_t)(rt * 4 + kk)) * 512 + lane * 8);
        s16x8 alo = ldfrag(P.xloF + ((size_t)(rt * 4 + kk)) * 512 + lane * 8);
        #pragma unroll
        for (int j = 0; j < 4; j++) {
            int ct = b * 128 + cs * 4 + j;
            s16x8 bhi = ldfrag(P.xhiF + ((size_t)(ct * 4 + kk)) * 512 + lane * 8);
            s16x8 blo = ldfrag(P.xloF + ((size_t)(ct * 4 + kk)) * 512 + lane * 8);
            acc[j] = __builtin_amdgcn_mfma_f32_16x16x32_bf16(ahi, bhi, acc[j], 0, 0, 0);
            acc[j] = __builtin_amdgcn_mfma_f32_16x16x32_bf16(alo, bhi, acc[j], 0, 0, 0);
            acc[j] = __builtin_amdgcn_mfma_f32_16x16x32_bf16(ahi, blo, acc[j], 0, 0, 0);
        }
    }
    int cl = lane & 15, quad = lane >> 4;
    #pragma unroll
    for (int j = 0; j < 4; j++) {
        int col = cs * 64 + j * 16 + cl;
        float xxv = P.xx[b * 2048 + col];
        #pragma unroll
        for (int r = 0; r < 4; r++)
            key[(size_t)(rtl * 16 + quad * 4 + r) * 2048 + col] = 2.0f * acc[j][r] - xxv;
    }
}

// ---------------------------------------------------------------------------
// Phase 2 (vb in [0,1024)): per-row top-20 with exact threshold prefilter.
// ---------------------------------------------------------------------------
#define MERGE(off) { float ov = __shfl_xor(bv, off); int oi = __shfl_xor(bi, off); \
                     if (ov > bv || (ov == bv && oi < bi)) { bv = ov; bi = oi; } }

__device__ void phase_topk(const KParams& P, int vb) {
    __shared__ float sv[4][256];
    __shared__ int   si[4][256];
    int t = threadIdx.x, w = t >> 6, lane = t & 63;
    int slab = vb >> 9;
    int rowl = (vb & 511) * 4 + w;
    const float* key = slab ? P.key1 : P.key0;
    int rowbase = slab * 2048;
    const float4* kr = reinterpret_cast<const float4*>(key + (size_t)rowl * 2048);
    float rv[32];
    #pragma unroll
    for (int j = 0; j < 8; j++) {
        float4 v = kr[j * 64 + lane];
        rv[j * 4 + 0] = v.x; rv[j * 4 + 1] = v.y;
        rv[j * 4 + 2] = v.z; rv[j * 4 + 3] = v.w;
    }
    float lm = rv[0];
    #pragma unroll
    for (int sl = 1; sl < 32; sl++) lm = fmaxf(lm, rv[sl]);
    float bs = lm;
    #pragma unroll
    for (int k = 2; k <= 64; k <<= 1) {
        #pragma unroll
        for (int j = k >> 1; j > 0; j >>= 1) {
            float o = __shfl_xor(bs, j);
            bool dirDesc = (lane & k) != 0;
            bool upper   = (lane & j) != 0;
            bs = (upper != dirDesc) ? fmaxf(bs, o) : fminf(bs, o);
        }
    }
    float T = __shfl(bs, 44);
    int cnt = 0;
    #pragma unroll
    for (int sl = 0; sl < 32; sl++) cnt += (rv[sl] >= T) ? 1 : 0;
    int inc = cnt;
    #pragma unroll
    for (int off = 1; off < 64; off <<= 1) {
        int o = __shfl_up(inc, off);
        if (lane >= off) inc += o;
    }
    int S = __shfl(inc, 63);
    int pos = inc - cnt;
    bool small = (S <= 256);
    if (small) {
        #pragma unroll
        for (int sl = 0; sl < 32; sl++) {
            if (rv[sl] >= T) {
                sv[w][pos] = rv[sl];
                si[w][pos] = (sl >> 2) * 256 + lane * 4 + (sl & 3);
                pos++;
            }
        }
    }
    __syncthreads();

    if (small) {
        float vl[4]; int il[4];
        #pragma unroll
        for (int s = 0; s < 4; s++) {
            int g = lane + s * 64;
            bool ok = g < S;
            vl[s] = ok ? sv[w][g] : -3.4e38f;
            il[s] = ok ? si[w][g] : 0x7FFFFFFF;
        }
        unsigned removed = 0u;
        for (int iter = 0; iter < KNN; iter++) {
            float bv = -3.4e38f; int bi = 0x7FFFFFFF;
            #pragma unroll
            for (int s = 0; s < 4; s++) {
                bool live = ((removed >> s) & 1u) == 0u;
                if (live && (vl[s] > bv || (vl[s] == bv && il[s] < bi))) {
                    bv = vl[s]; bi = il[s];
                }
            }
            MERGE(32) MERGE(16) MERGE(8) MERGE(4) MERGE(2) MERGE(1)
            if (lane == 0) P.idxb[(size_t)(rowbase + rowl) * KNN + iter] = bi & 2047;
            #pragma unroll
            for (int s = 0; s < 4; s++)
                if (il[s] == bi) removed |= 1u << s;
        }
    } else {
        unsigned removed = 0u;
        for (int iter = 0; iter < KNN; iter++) {
            float bv = -3.4e38f; int bi = 0;
            #pragma unroll
            for (int sl = 0; sl < 32; sl++) {
                bool live = ((removed >> sl) & 1u) == 0u;
                if (live && rv[sl] > bv) { bv = rv[sl]; bi = (sl >> 2) * 256 + lane * 4 + (sl & 3); }
            }
            MERGE(32) MERGE(16) MERGE(8) MERGE(4) MERGE(2) MERGE(1)
            bi &= 2047;
            if (lane == 0) P.idxb[(size_t)(rowbase + rowl) * KNN + iter] = bi;
            if (((bi >> 2) & 63) == lane) removed |= 1u << ((bi >> 8) * 4 + (bi & 3));
        }
    }
}

// ---------------------------------------------------------------------------
// Phase 3 (vb in [0,2048)): sparse mutual-KNN attention, 2 points per vb.
// ---------------------------------------------------------------------------
__device__ void phase_attn(const KParams& P, int vb) {
    __shared__ float sbuf[2][KNN * 4];
    __shared__ int   mlist[2][KNN];
    __shared__ int   cnt_s[2];
    int tt = threadIdx.x;
    int half = tt >> 7, t = tt & 127;
    int p = vb * 2 + half;
    int b = p >> 11, n = p & 2047;
    int bbase = b * NPT;
    int h = t >> 5;

    if ((tt >> 6) == half * 2) {
        int lane = tt & 63;
        bool fl = false; int m = 0;
        if (lane < KNN) {
            m = P.idxb[(size_t)p * KNN + lane] & 2047;
            const int4* mrow = reinterpret_cast<const int4*>(P.idxb + (size_t)(bbase + m) * KNN);
            int4 r0 = mrow[0], r1 = mrow[1], r2 = mrow[2], r3 = mrow[3], r4 = mrow[4];
            fl = (r0.x == n) || (r0.y == n) || (r0.z == n) || (r0.w == n)
              || (r1.x == n) || (r1.y == n) || (r1.z == n) || (r1.w == n)
              || (r2.x == n) || (r2.y == n) || (r2.z == n) || (r2.w == n)
              || (r3.x == n) || (r3.y == n) || (r3.z == n) || (r3.w == n)
              || (r4.x == n) || (r4.y == n) || (r4.z == n) || (r4.w == n);
        }
        unsigned long long mask = __ballot(fl);
        int pos = __popcll(mask & ((1ull << lane) - 1ull));
        if (fl) mlist[half][pos] = m;
        if (lane == 0) cnt_s[half] = (int)__popcll(mask);
    }
    __syncthreads();

    int cnt = cnt_s[half];
    float qv = P.qT[(size_t)p * 128 + t];
    for (int jj = 0; jj < cnt; jj++) {
        int m = mlist[half][jj];
        float prod = qv * P.kT[(size_t)(bbase + m) * 128 + t];
        prod += __shfl_xor(prod, 16);
        prod += __shfl_xor(prod, 8);
        prod += __shfl_xor(prod, 4);
        prod += __shfl_xor(prod, 2);
        prod += __shfl_xor(prod, 1);
        if ((t & 31) == 0) sbuf[half][jj * 4 + h] = prod * 0.17677669529663687f;
    }
    __syncthreads();

    float mx = -3.4e38f;
    for (int j = 0; j < cnt; j++) mx = fmaxf(mx, sbuf[half][j * 4 + h]);
    float den = 0.f;
    for (int j = 0; j < cnt; j++) den += expf(sbuf[half][j * 4 + h] - mx);
    float inv = (cnt > 0) ? (1.0f / den) : 0.0f;
    float acc = 0.f;
    for (int j = 0; j < cnt; j++) {
        float pw = expf(sbuf[half][j * 4 + h] - mx) * inv;
        acc += pw * P.vT[(size_t)(bbase + mlist[half][j]) * 128 + t];
    }
    P.avT[(size_t)p * 128 + t] = acc;
}

// ---------------------------------------------------------------------------
// Phase 4 (vb in [0,256)): h = w1x@x + W@av + b1p (MFMA K=256) + BN stats.
// ---------------------------------------------------------------------------
__device__ void phase_h(const KParams& P, int vb) {
    int t = threadIdx.x, cs = t >> 6, lane = t & 63;
    int rt = vb;
    int p0 = rt * 16;

    f32x4 acc[4];
    #pragma unroll
    for (int j = 0; j < 4; j++) acc[j] = (f32x4){0.f, 0.f, 0.f, 0.f};

    for (int kk = 0; kk < 8; kk++) {
        s16x8 ahi, alo;
        if (kk < 4) {
            ahi = ldfrag(P.xhiF + ((size_t)(rt * 4 + kk)) * 512 + lane * 8);
            alo = ldfrag(P.xloF + ((size_t)(rt * 4 + kk)) * 512 + lane * 8);
        } else {
            const float* arow = P.avT + (size_t)(p0 + (lane & 15)) * 128
                              + (kk - 4) * 32 + (lane >> 4) * 8;
            f8_hilo(arow, &ahi, &alo);
        }
        #pragma unroll
        for (int j = 0; j < 4; j++) {
            int nt = cs * 4 + j;
            s16x8 bhi = ldfrag(P.wcFhi + ((size_t)(nt * 8 + kk)) * 512 + lane * 8);
            s16x8 blo = ldfrag(P.wcFlo + ((size_t)(nt * 8 + kk)) * 512 + lane * 8);
            acc[j] = __builtin_amdgcn_mfma_f32_16x16x32_bf16(ahi, bhi, acc[j], 0, 0, 0);
            acc[j] = __builtin_amdgcn_mfma_f32_16x16x32_bf16(alo, bhi, acc[j], 0, 0, 0);
            acc[j] = __builtin_amdgcn_mfma_f32_16x16x32_bf16(ahi, blo, acc[j], 0, 0, 0);
        }
    }

    int cl = lane & 15, quad = lane >> 4;
    #pragma unroll
    for (int j = 0; j < 4; j++) {
        int o = cs * 64 + j * 16 + cl;
        float bb = P.b1p[o];
        float s = 0.f, s2 = 0.f;
        #pragma unroll
        for (int r = 0; r < 4; r++) {
            float v = acc[j][r] + bb;
            P.hbuf[(size_t)(p0 + quad * 4 + r) * 256 + o] = v;
            s += v; s2 += v * v;
        }
        s  += __shfl_xor(s, 16);  s  += __shfl_xor(s, 32);
        s2 += __shfl_xor(s2, 16); s2 += __shfl_xor(s2, 32);
        if (quad == 0) {
            atomicAdd(&P.stats[o], s);
            atomicAdd(&P.stats[256 + o], s2);
        }
    }
}

// ---------------------------------------------------------------------------
// Phase 5 (vb in [0,256)): out = w2@relu(BN(h)) + b2 + x (MFMA K=256).
// ---------------------------------------------------------------------------
__device__ void phase_out(const KParams& P, int vb) {
    int t = threadIdx.x, wvi = t >> 6, lane = t & 63;
    int rt = vb;
    int p0 = rt * 16;

    f32x4 acc[2];
    acc[0] = (f32x4){0.f, 0.f, 0.f, 0.f};
    acc[1] = (f32x4){0.f, 0.f, 0.f, 0.f};

    for (int kk = 0; kk < 8; kk++) {
        int c0 = kk * 32 + (lane >> 4) * 8;
        const float* hrow = P.hbuf + (size_t)(p0 + (lane & 15)) * 256 + c0;
        float4 f0 = *reinterpret_cast<const float4*>(hrow);
        float4 f1 = *reinterpret_cast<const float4*>(hrow + 4);
        float4 s0 = *reinterpret_cast<const float4*>(P.stats + c0);
        float4 s1 = *reinterpret_cast<const float4*>(P.stats + c0 + 4);
        float4 q0 = *reinterpret_cast<const float4*>(P.stats + 256 + c0);
        float4 q1 = *reinterpret_cast<const float4*>(P.stats + 256 + c0 + 4);
        float4 g0 = *reinterpret_cast<const float4*>(P.gamma + c0);
        float4 g1 = *reinterpret_cast<const float4*>(P.gamma + c0 + 4);
        float4 e0 = *reinterpret_cast<const float4*>(P.beta + c0);
        float4 e1 = *reinterpret_cast<const float4*>(P.beta + c0 + 4);
        float f[8] = {f0.x, f0.y, f0.z, f0.w, f1.x, f1.y, f1.z, f1.w};
        float sm[8] = {s0.x, s0.y, s0.z, s0.w, s1.x, s1.y, s1.z, s1.w};
        float sq[8] = {q0.x, q0.y, q0.z, q0.w, q1.x, q1.y, q1.z, q1.w};
        float gm[8] = {g0.x, g0.y, g0.z, g0.w, g1.x, g1.y, g1.z, g1.w};
        float bt[8] = {e0.x, e0.y, e0.z, e0.w, e1.x, e1.y, e1.z, e1.w};
        union { ushort u[8]; s16x8 s; } H, L;
        #pragma unroll
        for (int j = 0; j < 8; j++) {
            float mu  = sm[j] * (1.0f / 4096.0f);
            float var = fmaxf(sq[j] * (1.0f / 4096.0f) - mu * mu, 0.0f);
            float a    = gm[j] / sqrtf(var + 1e-5f);
            float cadd = bt[j] - mu * a;
            float v = fmaxf(f[j] * a + cadd, 0.0f);
            ushort hi = f2bf_rne(v);
            H.u[j] = hi;
            L.u[j] = f2bf_rne(v - bfbits2f(hi));
        }
        s16x8 ahi = H.s, alo = L.s;
        #pragma unroll
        for (int jj = 0; jj < 2; jj++) {
            int nt = wvi * 2 + jj;
            s16x8 bhi = ldfrag(P.w2Fhi + ((size_t)(nt * 8 + kk)) * 512 + lane * 8);
            s16x8 blo = ldfrag(P.w2Flo + ((size_t)(nt * 8 + kk)) * 512 + lane * 8);
            acc[jj] = __builtin_amdgcn_mfma_f32_16x16x32_bf16(ahi, bhi, acc[jj], 0, 0, 0);
            acc[jj] = __builtin_amdgcn_mfma_f32_16x16x32_bf16(alo, bhi, acc[jj], 0, 0, 0);
            acc[jj] = __builtin_amdgcn_mfma_f32_16x16x32_bf16(ahi, blo, acc[jj], 0, 0, 0);
        }
    }
    int cl = lane & 15, quad = lane >> 4;
    int b = p0 >> 11, n0 = p0 & 2047;
    #pragma unroll
    for (int jj = 0; jj < 2; jj++) {
        int o = (wvi * 2 + jj) * 16 + cl;
        float bb = P.b2[o];
        size_t base = (size_t)b * 128 * NPT + (size_t)o * NPT + n0 + quad * 4;
        float4 xv = *reinterpret_cast<const float4*>(P.xbf + base);
        float4 ov;
        ov.x = acc[jj][0] + bb + xv.x;
        ov.y = acc[jj][1] + bb + xv.y;
        ov.z = acc[jj][2] + bb + xv.z;
        ov.w = acc[jj][3] + bb + xv.w;
        *reinterpret_cast<float4*>(P.out + base) = ov;
    }
}

// 6-dispatch wrappers — stream dispatch boundaries are the cheap grid-wide
// barrier on MI355X (coop grid.sync measured ~100 µs each: round-13 mega).
__global__ __launch_bounds__(256) void w_prep(KParams P) { phase_prep(P, blockIdx.x); }
__global__ __launch_bounds__(256) void w_gemm(KParams P) { phase_gemm(P, blockIdx.x); }
__global__ __launch_bounds__(256) void w_topk(KParams P) { phase_topk(P, blockIdx.x); }
__global__ __launch_bounds__(256) void w_attn(KParams P) { phase_attn(P, blockIdx.x); }
__global__ __launch_bounds__(256) void w_h(KParams P)    { phase_h(P, blockIdx.x); }
__global__ __launch_bounds__(256) void w_out(KParams P)  { phase_out(P, blockIdx.x); }

// ---------------------------------------------------------------------------
// Workspace layout (44,978,176 B; observed ws ≈ 268 MB): same as round 12.
// ---------------------------------------------------------------------------
#define WS_FULL 44978176u

extern "C" void kernel_launch(void* const* d_in, const int* in_sizes, int n_in,
                              void* d_out, int out_size, void* d_ws, size_t ws_size,
                              hipStream_t stream) {
    if (ws_size < (size_t)WS_FULL) return;  // all-zero out => ws too small

    char* ws = (char*)d_ws;
    KParams P;
    P.xbf = (fp)d_in[0];
    P.wq = (fp)d_in[1];  P.bq = (fp)d_in[2];
    P.wk = (fp)d_in[3];  P.bk = (fp)d_in[4];
    P.wv = (fp)d_in[5];  P.bv = (fp)d_in[6];
    P.wm = (fp)d_in[7];  P.bm = (fp)d_in[8];
    P.w1 = (fp)d_in[9];  P.b1 = (fp)d_in[10];
    P.gamma = (fp)d_in[11]; P.beta = (fp)d_in[12];
    P.w2 = (fp)d_in[13]; P.b2 = (fp)d_in[14];
    P.qT    = (float*) (ws + 0);
    P.kT    = (float*) (ws + 2097152);
    P.vT    = (float*) (ws + 4194304);
    P.avT   = (float*) (ws + 6291456);
    P.xx    = (float*) (ws + 8388608);
    P.idxb  = (int*)   (ws + 8404992);
    P.stats = (float*) (ws + 8732672);
    P.b1p   = (float*) (ws + 8734720);
    P.wqFhi = (ushort*)(ws + 8736768);
    P.wqFlo = (ushort*)(ws + 8769536);
    P.wkFhi = (ushort*)(ws + 8802304);
    P.wkFlo = (ushort*)(ws + 8835072);
    P.wvFhi = (ushort*)(ws + 8867840);
    P.wvFlo = (ushort*)(ws + 8900608);
    P.wcFhi = (ushort*)(ws + 8933376);
    P.wcFlo = (ushort*)(ws + 9064448);
    P.w2Fhi = (ushort*)(ws + 9195520);
    P.w2Flo = (ushort*)(ws + 9261056);
    P.xhiF  = (ushort*)(ws + 9326592);
    P.xloF  = (ushort*)(ws + 10375168);
    P.key0  = (float*) (ws + 11423744);
    P.key1  = (float*) (ws + 28200960);
    P.hbuf  = (float*) (ws + 0);            // aliases qT+kT (dead after attn)
    P.out   = (float*)d_out;

    w_prep<<<835, 256, 0, stream>>>(P);
    w_gemm<<<2432, 256, 0, stream>>>(P);
    w_topk<<<1024, 256, 0, stream>>>(P);
    w_attn<<<2048, 256, 0, stream>>>(P);
    w_h<<<256, 256, 0, stream>>>(P);
    w_out<<<256, 256, 0, stream>>>(P);
}